// Round 9
// baseline (176.345 us; speedup 1.0000x reference)
//
#include <hip/hip_runtime.h>

#define NBOX 300000
#define NFEAT 85
#define NCLS 80
#define NBUCK 4096
#define HSPLIT 16
#define CMAX 8192
#define W64 (CMAX / 64)   // 128 mask words per candidate row
#define MAXKEEP 1000
#define PRE 24            // register-prefetch rows per compact block
#define SC_ROWS 64        // k_scores tile rows

typedef unsigned long long u64;
typedef float f4a __attribute__((ext_vector_type(4), aligned(16)));

__device__ __forceinline__ int bucket_of(float s) {
    int b = (int)((s - 0.3f) * (4096.0f / 0.7f));
    if (b < 0) b = 0;
    if (b > NBUCK - 1) b = NBUCK - 1;
    return b;
}

__device__ __forceinline__ bool sup_iou(float by1, float bx1, float by2, float bx2, float ba,
                                        float y1, float x1, float y2, float x2, float area) {
    float iy1 = fmaxf(by1, y1), ix1 = fmaxf(bx1, x1);
    float iy2 = fminf(by2, y2), ix2 = fminf(bx2, x2);
    float inter = fmaxf(iy2 - iy1, 0.0f) * fmaxf(ix2 - ix1, 0.0f);
    float uni = ba + area - inter;
    float iou = (uni > 0.0f) ? inter / uni : 0.0f;
    return iou > 0.5f;
}

__global__ void k_init(unsigned* __restrict__ hist16, unsigned* __restrict__ cnt,
                       int* __restrict__ meta) {
    int i = blockIdx.x * blockDim.x + threadIdx.x;
    if (i < HSPLIT * NBUCK) hist16[i] = 0u;
    if (i < NBUCK) cnt[i] = 0u;
    if (i < 16) meta[i] = 0;
}

// Coalesced staged scores (R8 structure) + 16-way split histograms (atomic
// contention /16). conf*max(p) == max(conf*p) exactly (conf>=0, RN monotone).
__global__ void __launch_bounds__(256) k_scores(const float* __restrict__ in,
        float* __restrict__ scores, unsigned* __restrict__ hist16) {
    __shared__ float lds[SC_ROWS * NFEAT];  // 21760 B
    int t = threadIdx.x;
    long long rbase = (long long)blockIdx.x * SC_ROWS;
    int rows = (NBOX - rbase < SC_ROWS) ? (int)(NBOX - rbase) : SC_ROWS;
    int nfl = rows * NFEAT;
    int nf4 = nfl >> 2;
    const f4a* src = (const f4a*)(in + rbase * NFEAT);
    f4a* dst = (f4a*)lds;
    for (int k = t; k < nf4; k += 256) dst[k] = src[k];
    for (int k = (nf4 << 2) + t; k < nfl; k += 256) lds[k] = in[rbase * NFEAT + k];
    __syncthreads();
    unsigned* myhist = hist16 + (size_t)(blockIdx.x & (HSPLIT - 1)) * NBUCK;
    int row = t >> 2, part = t & 3;
    if (row < rows) {
        const float* r = lds + row * NFEAT;
        const float* p = r + 5 + 20 * part;
        float mx = p[0];
        #pragma unroll
        for (int j = 1; j < 20; ++j) mx = fmaxf(mx, p[j]);
        mx = fmaxf(mx, __shfl_xor(mx, 1));
        mx = fmaxf(mx, __shfl_xor(mx, 2));
        if (part == 0) {
            float best = r[4] * mx;
            scores[rbase + row] = best;
            if (best >= 0.3f) atomicAdd(&myhist[bucket_of(best)], 1u);
        }
    }
}

// Sum split hists; suffix sums; bstar = smallest b with suffix(b) <= CMAX;
// off[b] = suffix(b+1); histsum[b] = bucket size; meta[0]=count, meta[1]=bstar.
__global__ void __launch_bounds__(1024) k_thresh(const unsigned* __restrict__ hist16,
        unsigned* __restrict__ histsum, unsigned* __restrict__ off, int* __restrict__ meta) {
    __shared__ unsigned chunk[1024];
    int t = threadIdx.x;
    unsigned h[4];
    unsigned s = 0;
    #pragma unroll
    for (int j = 0; j < 4; ++j) {
        unsigned v = 0;
        for (int g = 0; g < HSPLIT; ++g) v += hist16[g * NBUCK + t * 4 + j];
        h[j] = v; histsum[t * 4 + j] = v; s += v;
    }
    chunk[t] = s;
    __syncthreads();
    for (int o = 1; o < 1024; o <<= 1) {
        unsigned add = (t + o < 1024) ? chunk[t + o] : 0u;
        __syncthreads();
        chunk[t] += add;
        __syncthreads();
    }
    unsigned after = (t + 1 < 1024) ? chunk[t + 1] : 0u;
    unsigned suf[5];
    suf[4] = after;
    #pragma unroll
    for (int j = 3; j >= 0; --j) suf[j] = suf[j + 1] + h[j];
    #pragma unroll
    for (int j = 0; j < 4; ++j) {
        int b = t * 4 + j;
        off[b] = suf[j] - h[j];
        unsigned sufb = suf[j];
        unsigned sufprev;
        if (b == 0) sufprev = 0xFFFFFFFFu;
        else if (j > 0) sufprev = suf[j - 1];
        else {
            unsigned hprev = 0;
            for (int g = 0; g < HSPLIT; ++g) hprev += hist16[g * NBUCK + b - 1];
            sufprev = sufb + hprev;
        }
        if (sufb <= (unsigned)CMAX && sufprev > (unsigned)CMAX) {
            meta[1] = b;
            meta[0] = (int)sufb;
        }
    }
}

__global__ void k_scatter(const float* __restrict__ scores, const int* __restrict__ meta,
                          const unsigned* __restrict__ off, unsigned* __restrict__ cnt,
                          u64* __restrict__ unsorted) {
    int i = blockIdx.x * blockDim.x + threadIdx.x;
    if (i >= NBOX) return;
    float s = scores[i];
    if (s < 0.3f) return;
    int b = bucket_of(s);
    if (b < meta[1]) return;
    unsigned slot = off[b] + atomicAdd(&cnt[b], 1u);
    if (slot < CMAX)
        unsorted[slot] = ((u64)__float_as_uint(s) << 32) |
                         (u64)(0xFFFFFFFFu - (unsigned)i);
}

// Exact rank within bucket -> fully sorted, deterministic. Also compacts the box
// into boxes4 and emits vflag (both extents strictly positive).
__global__ void k_rank(const float* __restrict__ in, const u64* __restrict__ unsorted,
                       const unsigned* __restrict__ off, const unsigned* __restrict__ histsum,
                       const int* __restrict__ meta, u64* __restrict__ sorted,
                       float4* __restrict__ boxes4, unsigned* __restrict__ vflag) {
    int i = blockIdx.x * blockDim.x + threadIdx.x;
    int total = meta[0];
    if (i >= total) return;
    u64 k = unsorted[i];
    float s = __uint_as_float((unsigned)(k >> 32));
    int b = bucket_of(s);
    unsigned base = off[b];
    unsigned n = histsum[b];
    unsigned r = 0;
    for (unsigned u = 0; u < n; ++u) r += (unsorted[base + u] > k) ? 1u : 0u;
    int bi = (int)(0xFFFFFFFFu - (unsigned)(k & 0xFFFFFFFFull));
    const float* p = in + (size_t)bi * NFEAT;
    float4 bx = make_float4(p[0], p[1], p[2], p[3]);  // y1,x1,y2,x2
    sorted[base + r] = k;
    boxes4[base + r] = bx;
    vflag[base + r] = (bx.z > bx.x && bx.w > bx.y) ? 1u : 0u;
}

// Prefix-scan valid flags; build compact map + compact boxes; meta[3] = nvalid.
// Degenerate boxes have IoU==0 with everything (inter extents clamp to 0):
// never suppress, never suppressed -> excluded from masks/sweep, always kept.
__global__ void __launch_bounds__(1024) k_vscan(const unsigned* __restrict__ vflag,
        const float4* __restrict__ boxes4, int* __restrict__ meta,
        unsigned* __restrict__ vincl, unsigned* __restrict__ cmap,
        float4* __restrict__ cboxes) {
    __shared__ unsigned ps[1024];
    int t = threadIdx.x;
    int total = meta[0];
    unsigned f[8];
    unsigned run = 0;
    #pragma unroll
    for (int e = 0; e < 8; ++e) {
        int s = t * 8 + e;
        unsigned v = (s < total) ? vflag[s] : 0u;
        run += v;
        f[e] = run;
    }
    ps[t] = run;
    __syncthreads();
    for (int o = 1; o < 1024; o <<= 1) {
        unsigned add = (t >= o) ? ps[t - o] : 0u;
        __syncthreads();
        ps[t] += add;
        __syncthreads();
    }
    unsigned excl = (t > 0) ? ps[t - 1] : 0u;
    #pragma unroll
    for (int e = 0; e < 8; ++e) {
        int s = t * 8 + e;
        unsigned incl = excl + f[e];
        vincl[s] = incl;
        if (s < total && vflag[s]) {
            cmap[incl - 1] = (unsigned)s;
            cboxes[incl - 1] = boxes4[s];
        }
    }
    if (t == 1023) meta[3] = (int)ps[1023];
}

// Pairwise masks over COMPACT valid candidates: masks[i][w] bit b = (j=w*64+b) > i
// && IoU>0.5. Words tj >= ti written; sub-diagonal garbage never effectively read.
__global__ void __launch_bounds__(256) k_masks(const float4* __restrict__ cboxes,
        const int* __restrict__ meta, u64* __restrict__ masks) {
    int ti = blockIdx.y, tj = blockIdx.x;
    if (tj < ti) return;
    int count = meta[3];
    if (ti * 64 >= count) return;
    __shared__ float4 rb[64];
    int t = threadIdx.x;
    if (t < 64) {
        int r = ti * 64 + t;
        rb[t] = (r < count) ? cboxes[r] : make_float4(0.f, 0.f, 0.f, 0.f);
    }
    int lane = t & 63, wid = t >> 6;
    int cj = tj * 64 + lane;
    bool cvalid = (cj < count);
    float4 cb = cvalid ? cboxes[cj] : make_float4(0.f, 0.f, 0.f, 0.f);
    float carea = (cb.z - cb.x) * (cb.w - cb.y);
    __syncthreads();
    #pragma unroll
    for (int r = 0; r < 16; ++r) {
        int i = ti * 64 + wid * 16 + r;
        float4 b = rb[wid * 16 + r];
        float ba = (b.z - b.x) * (b.w - b.y);
        bool s = cvalid && (cj > i) && (i < count) &&
                 sup_iou(b.x, b.y, b.z, b.w, ba, cb.x, cb.y, cb.z, cb.w, carea);
        u64 word = __ballot(s ? 1 : 0);
        if (lane == 0) masks[(size_t)i * W64 + tj] = word;
    }
}

// Wave 0: greedy sweep over compact candidates (register speculative prefetch,
// double-buffered static arrays). Stops once merged kept (invalid-by-slot +
// valid-kept) reaches MAXKEEP. Then all 1024 threads: finalize scan -> kfinal.
__global__ void __launch_bounds__(1024) k_sweepfin(const u64* __restrict__ masks,
        const unsigned* __restrict__ cmap, const unsigned* __restrict__ vincl,
        const unsigned* __restrict__ vflag, int* __restrict__ meta,
        int* __restrict__ kfinal) {
    __shared__ u64 vkeptw[W64];
    __shared__ unsigned ps[1024];
    __shared__ int sh_wlim;
    int t = threadIdx.x;
    if (t < W64) vkeptw[t] = 0ull;
    if (t == 0) sh_wlim = 0;
    __syncthreads();
    int total = meta[0];
    int nv = meta[3];

    if (t < 64) {  // ---- sweep wave ----
        int lane = t;
        int nblkv = (nv + 63) >> 6;
        u64 r0 = 0ull, r1 = 0ull;
        int nkv = 0, wl = 0;
        u64 pa_lo[PRE], pa_hi[PRE], pb_lo[PRE], pb_hi[PRE];
        u64 spec_cur = 0ull, spec_next = 0ull, diag_cur = 0ull, diag_next = 0ull;

        if (nblkv > 0) {  // prologue: block 0 spec is exact (R=0)
            spec_cur = (nv >= 64) ? ~0ull : ((1ull << nv) - 1ull);
            u64 tt = spec_cur;
            #pragma unroll
            for (int k = 0; k < PRE; ++k) {
                bool has = (tt != 0ull);
                int b = has ? (__ffsll(tt) - 1) : 0;
                tt &= tt - 1;
                const u64* p = masks + (size_t)b * W64 + 2 * lane;
                pa_lo[k] = p[0]; pa_hi[k] = p[1];
            }
            diag_cur = masks[(size_t)lane * W64];
        }

        for (int w = 0; w < nblkv; ++w) {
            int base = w << 6;
            int rc = nv - base;
            u64 vm = (rc >= 64) ? ~0ull : ((1ull << rc) - 1ull);
            u64 rw = __shfl((w & 1) ? r1 : r0, w >> 1);
            u64 surv = ~rw & vm;
            int cend = (base + 63 < nv - 1) ? (base + 63) : (nv - 1);
            unsigned cm = cmap[cend];
            bool more = (w + 1 < nblkv);
            if (more) {  // speculative issue for w+1 (R lags one block: superset-safe)
                int b2 = base + 64, w2 = w + 1;
                int rc2 = nv - b2;
                u64 vm2 = (rc2 >= 64) ? ~0ull : ((1ull << rc2) - 1ull);
                u64 rw2 = __shfl((w2 & 1) ? r1 : r0, w2 >> 1);
                spec_next = ~rw2 & vm2;
                u64 tt = spec_next;
                #pragma unroll
                for (int k = 0; k < PRE; ++k) {
                    bool has = (tt != 0ull);
                    int b = has ? (__ffsll(tt) - 1) : 0;
                    tt &= tt - 1;
                    const u64* p = masks + (size_t)(b2 + b) * W64 + 2 * lane;
                    pb_lo[k] = p[0]; pb_hi[k] = p[1];
                }
                diag_next = masks[(size_t)(b2 + lane) * W64 + w2];
            }
            // in-block greedy chain (nonzero-diag candidates only)
            u64 Z = __ballot(diag_cur == 0ull);
            u64 rem = 0ull;
            u64 mnz = surv & ~Z;
            while (mnz) {
                int b = __ffsll(mnz) - 1;
                mnz &= mnz - 1;
                if ((rem >> b) & 1ull) continue;
                u64 db = __shfl(diag_cur, b);
                rem |= db;
                mnz &= ~db;
            }
            u64 kept = surv & ~rem;
            int kp = __popcll(kept);
            // R-update: prefetched regs (walk mirrors issue walk) + fallback
            {
                u64 tt = spec_cur;
                u64 alo = 0ull, ahi = 0ull;
                #pragma unroll
                for (int k = 0; k < PRE; ++k) {
                    bool has = (tt != 0ull);
                    int b = has ? (__ffsll(tt) - 1) : 0;
                    tt &= tt - 1;
                    bool use = has && (((kept >> b) & 1ull) != 0ull);
                    alo |= use ? pa_lo[k] : 0ull;
                    ahi |= use ? pa_hi[k] : 0ull;
                }
                u64 km = kept & tt;
                while (km) {
                    int b = __ffsll(km) - 1;
                    km &= km - 1;
                    const u64* p = masks + (size_t)(base + b) * W64 + 2 * lane;
                    alo |= p[0]; ahi |= p[1];
                }
                r0 |= alo; r1 |= ahi;
            }
            if (lane == 0) vkeptw[w] = kept;
            nkv += kp;
            wl = w + 1;
            // merged kept through slot cmap[cend]: invalids (cmap[cend]-cend) + valid-kept
            if ((int)cm - cend + nkv >= MAXKEEP) break;
            #pragma unroll
            for (int k = 0; k < PRE; ++k) { pa_lo[k] = pb_lo[k]; pa_hi[k] = pb_hi[k]; }
            spec_cur = spec_next;
            diag_cur = diag_next;
        }
        if (lane == 0) sh_wlim = wl;
    }
    __syncthreads();
    int wlim = sh_wlim;

    // ---- finalize: kept(s) = invalid(s) OR valid-kept(s); first MAXKEEP ----
    unsigned f[8];
    unsigned run = 0;
    #pragma unroll
    for (int e = 0; e < 8; ++e) {
        int s = t * 8 + e;
        unsigned kept = 0u;
        if (s < total) {
            if (!vflag[s]) kept = 1u;
            else {
                unsigned c = vincl[s] - 1u;
                int w = (int)(c >> 6);
                if (w < wlim && ((vkeptw[w] >> (c & 63u)) & 1ull)) kept = 1u;
            }
        }
        run += kept;
        f[e] = run;
    }
    ps[t] = run;
    __syncthreads();
    for (int o = 1; o < 1024; o <<= 1) {
        unsigned add = (t >= o) ? ps[t - o] : 0u;
        __syncthreads();
        ps[t] += add;
        __syncthreads();
    }
    unsigned excl = (t > 0) ? ps[t - 1] : 0u;
    #pragma unroll
    for (int e = 0; e < 8; ++e) {
        int s = t * 8 + e;
        unsigned kept = 0u;
        if (s < total) {
            if (!vflag[s]) kept = 1u;
            else {
                unsigned c = vincl[s] - 1u;
                int w = (int)(c >> 6);
                if (w < wlim && ((vkeptw[w] >> (c & 63u)) & 1ull)) kept = 1u;
            }
        }
        unsigned incl = excl + f[e];
        if (kept && incl <= (unsigned)MAXKEEP) kfinal[incl - 1] = s;
    }
    if (t == 1023) {
        unsigned tot = ps[1023];
        meta[2] = (int)(tot < (unsigned)MAXKEEP ? tot : (unsigned)MAXKEEP);
    }
}

// One wave per output row: butterfly argmax, strict-greater / lower-index
// tiebreak (== jnp.argmax first occurrence).
__global__ void __launch_bounds__(256) k_output(const float* __restrict__ in,
        const u64* __restrict__ gkeys, const int* __restrict__ meta,
        const int* __restrict__ kfinal, float* __restrict__ out) {
    int gw = (blockIdx.x * blockDim.x + threadIdx.x) >> 6;
    int lane = threadIdx.x & 63;
    if (gw >= MAXKEEP) return;
    int kc = meta[2];
    if (gw < kc) {
        int pos = kfinal[gw];
        u64 key = gkeys[pos];
        int bi = (int)(0xFFFFFFFFu - (unsigned)(key & 0xFFFFFFFFull));
        const float* row = in + (size_t)bi * NFEAT;
        float conf = row[4];
        float v0 = (lane < NCLS) ? conf * row[5 + lane] : -1.0f;
        float v1 = (lane < NCLS - 64) ? conf * row[5 + 64 + lane] : -1.0f;
        float bv = (v1 > v0) ? v1 : v0;
        int bix = (v1 > v0) ? (64 + lane) : lane;
        #pragma unroll
        for (int o = 1; o < 64; o <<= 1) {
            float ov = __shfl_xor(bv, o);
            int oi = __shfl_xor(bix, o);
            if (ov > bv || (ov == bv && oi < bix)) { bv = ov; bix = oi; }
        }
        float wv = 0.f;
        if (lane < 4) wv = row[lane];
        else if (lane == 4) wv = (float)bix;
        else wv = bv;
        if (lane < 6) out[gw * 6 + lane] = wv;
    } else {
        if (lane < 6) out[gw * 6 + lane] = 0.f;
    }
}

extern "C" void kernel_launch(void* const* d_in, const int* in_sizes, int n_in,
                              void* d_out, int out_size, void* d_ws, size_t ws_size,
                              hipStream_t stream) {
    const float* in = (const float*)d_in[0];
    float* out = (float*)d_out;
    char* ws = (char*)d_ws;
    // ws layout (bytes). masks OVERLAYS sort-phase scratch (all dead before k_masks).
    //   [0, 65536)           sorted   u64[8192]
    //   [65536, 65600)       meta     i32[16] {0:total,1:bstar,2:kc,3:nvalid}
    //   [65600, 69696)       kfinal   i32[1024]
    //   [69696, 102464)      vflag    u32[8192]
    //   [102464, 135232)     vincl    u32[8192]
    //   [135232, 168000)     cmap     u32[8192]
    //   [168000, 299072)     cboxes   float4[8192]
    //   [299072, 430144)     boxes4   float4[8192]
    //   [430144, 8818752)    masks    u64[8192*128] (8 MB), overlaying:
    //     [430144, 1630144)    scores   f32[300000]
    //     [1630144, 1892288)   hist16   u32[16*4096]
    //     [1892288, 1908672)   histsum  u32[4096]
    //     [1908672, 1925056)   cnt      u32[4096]
    //     [1925056, 1941440)   off      u32[4096]
    //     [1941440, 2006976)   unsorted u64[8192]
    u64* sorted = (u64*)(ws);
    int* meta = (int*)(ws + 65536);
    int* kfinal = (int*)(ws + 65600);
    unsigned* vflag = (unsigned*)(ws + 69696);
    unsigned* vincl = (unsigned*)(ws + 102464);
    unsigned* cmap = (unsigned*)(ws + 135232);
    float4* cboxes = (float4*)(ws + 168000);
    float4* boxes4 = (float4*)(ws + 299072);
    u64* masks = (u64*)(ws + 430144);
    float* scores = (float*)(ws + 430144);
    unsigned* hist16 = (unsigned*)(ws + 1630144);
    unsigned* histsum = (unsigned*)(ws + 1892288);
    unsigned* cnt = (unsigned*)(ws + 1908672);
    unsigned* off = (unsigned*)(ws + 1925056);
    u64* unsorted = (u64*)(ws + 1941440);

    k_init<<<dim3(256), dim3(256), 0, stream>>>(hist16, cnt, meta);
    k_scores<<<dim3((NBOX + SC_ROWS - 1) / SC_ROWS), dim3(256), 0, stream>>>(in, scores, hist16);
    k_thresh<<<dim3(1), dim3(1024), 0, stream>>>(hist16, histsum, off, meta);
    k_scatter<<<dim3((NBOX + 255) / 256), dim3(256), 0, stream>>>(scores, meta, off, cnt, unsorted);
    k_rank<<<dim3(CMAX / 256), dim3(256), 0, stream>>>(in, unsorted, off, histsum, meta, sorted, boxes4, vflag);
    k_vscan<<<dim3(1), dim3(1024), 0, stream>>>(vflag, boxes4, meta, vincl, cmap, cboxes);
    k_masks<<<dim3(W64, W64), dim3(256), 0, stream>>>(cboxes, meta, masks);
    k_sweepfin<<<dim3(1), dim3(1024), 0, stream>>>(masks, cmap, vincl, vflag, meta, kfinal);
    k_output<<<dim3((MAXKEEP * 64 + 255) / 256), dim3(256), 0, stream>>>(in, sorted, meta, kfinal, out);
}

// Round 10
// 130.536 us; speedup vs baseline: 1.3509x; 1.3509x over previous
//
#include <hip/hip_runtime.h>

#define NBOX 300000
#define NFEAT 85
#define NCLS 80
#define NBUCK 4096
#define HSPLIT 16
#define CMAX 8192
#define W64 (CMAX / 64)   // 128 mask words per candidate row
#define MAXKEEP 1000
#define SC_ROWS 64        // k_scores tile rows

typedef unsigned long long u64;
typedef float f4a __attribute__((ext_vector_type(4), aligned(16)));

__device__ __forceinline__ int bucket_of(float s) {
    int b = (int)((s - 0.3f) * (4096.0f / 0.7f));
    if (b < 0) b = 0;
    if (b > NBUCK - 1) b = NBUCK - 1;
    return b;
}

__device__ __forceinline__ bool sup_iou(float by1, float bx1, float by2, float bx2, float ba,
                                        float y1, float x1, float y2, float x2, float area) {
    float iy1 = fmaxf(by1, y1), ix1 = fmaxf(bx1, x1);
    float iy2 = fminf(by2, y2), ix2 = fminf(bx2, x2);
    float inter = fmaxf(iy2 - iy1, 0.0f) * fmaxf(ix2 - ix1, 0.0f);
    float uni = ba + area - inter;
    float iou = (uni > 0.0f) ? inter / uni : 0.0f;
    return iou > 0.5f;
}

__global__ void k_init(unsigned* __restrict__ hist16, unsigned* __restrict__ cnt,
                       int* __restrict__ meta) {
    int i = blockIdx.x * blockDim.x + threadIdx.x;
    if (i < HSPLIT * NBUCK) hist16[i] = 0u;
    if (i < NBUCK) cnt[i] = 0u;
    if (i < 16) meta[i] = 0;
}

// Coalesced staged scores + 16-way split histograms (atomic contention /16).
// conf*max(p) == max(conf*p) exactly (conf>=0, RN monotone).
__global__ void __launch_bounds__(256) k_scores(const float* __restrict__ in,
        float* __restrict__ scores, unsigned* __restrict__ hist16) {
    __shared__ float lds[SC_ROWS * NFEAT];  // 21760 B
    int t = threadIdx.x;
    long long rbase = (long long)blockIdx.x * SC_ROWS;
    int rows = (NBOX - rbase < SC_ROWS) ? (int)(NBOX - rbase) : SC_ROWS;
    int nfl = rows * NFEAT;
    int nf4 = nfl >> 2;
    const f4a* src = (const f4a*)(in + rbase * NFEAT);
    f4a* dst = (f4a*)lds;
    for (int k = t; k < nf4; k += 256) dst[k] = src[k];
    for (int k = (nf4 << 2) + t; k < nfl; k += 256) lds[k] = in[rbase * NFEAT + k];
    __syncthreads();
    unsigned* myhist = hist16 + (size_t)(blockIdx.x & (HSPLIT - 1)) * NBUCK;
    int row = t >> 2, part = t & 3;
    if (row < rows) {
        const float* r = lds + row * NFEAT;
        const float* p = r + 5 + 20 * part;
        float mx = p[0];
        #pragma unroll
        for (int j = 1; j < 20; ++j) mx = fmaxf(mx, p[j]);
        mx = fmaxf(mx, __shfl_xor(mx, 1));
        mx = fmaxf(mx, __shfl_xor(mx, 2));
        if (part == 0) {
            float best = r[4] * mx;
            scores[rbase + row] = best;
            if (best >= 0.3f) atomicAdd(&myhist[bucket_of(best)], 1u);
        }
    }
}

// Sum split hists; suffix sums; bstar = smallest b with suffix(b) <= CMAX;
// off[b] = suffix(b+1); histsum[b] = bucket size; meta[0]=count, meta[1]=bstar.
__global__ void __launch_bounds__(1024) k_thresh(const unsigned* __restrict__ hist16,
        unsigned* __restrict__ histsum, unsigned* __restrict__ off, int* __restrict__ meta) {
    __shared__ unsigned chunk[1024];
    int t = threadIdx.x;
    unsigned h[4];
    unsigned s = 0;
    #pragma unroll
    for (int j = 0; j < 4; ++j) {
        unsigned v = 0;
        for (int g = 0; g < HSPLIT; ++g) v += hist16[g * NBUCK + t * 4 + j];
        h[j] = v; histsum[t * 4 + j] = v; s += v;
    }
    chunk[t] = s;
    __syncthreads();
    for (int o = 1; o < 1024; o <<= 1) {
        unsigned add = (t + o < 1024) ? chunk[t + o] : 0u;
        __syncthreads();
        chunk[t] += add;
        __syncthreads();
    }
    unsigned after = (t + 1 < 1024) ? chunk[t + 1] : 0u;
    unsigned suf[5];
    suf[4] = after;
    #pragma unroll
    for (int j = 3; j >= 0; --j) suf[j] = suf[j + 1] + h[j];
    #pragma unroll
    for (int j = 0; j < 4; ++j) {
        int b = t * 4 + j;
        off[b] = suf[j] - h[j];
        unsigned sufb = suf[j];
        unsigned sufprev;
        if (b == 0) sufprev = 0xFFFFFFFFu;
        else if (j > 0) sufprev = suf[j - 1];
        else {
            unsigned hprev = 0;
            for (int g = 0; g < HSPLIT; ++g) hprev += hist16[g * NBUCK + b - 1];
            sufprev = sufb + hprev;
        }
        if (sufb <= (unsigned)CMAX && sufprev > (unsigned)CMAX) {
            meta[1] = b;
            meta[0] = (int)sufb;
        }
    }
}

__global__ void k_scatter(const float* __restrict__ scores, const int* __restrict__ meta,
                          const unsigned* __restrict__ off, unsigned* __restrict__ cnt,
                          u64* __restrict__ unsorted) {
    int i = blockIdx.x * blockDim.x + threadIdx.x;
    if (i >= NBOX) return;
    float s = scores[i];
    if (s < 0.3f) return;
    int b = bucket_of(s);
    if (b < meta[1]) return;
    unsigned slot = off[b] + atomicAdd(&cnt[b], 1u);
    if (slot < CMAX)
        unsorted[slot] = ((u64)__float_as_uint(s) << 32) |
                         (u64)(0xFFFFFFFFu - (unsigned)i);
}

// Exact rank within bucket -> fully sorted, deterministic. Also compacts the box
// into boxes4 and emits vflag (both extents strictly positive).
__global__ void k_rank(const float* __restrict__ in, const u64* __restrict__ unsorted,
                       const unsigned* __restrict__ off, const unsigned* __restrict__ histsum,
                       const int* __restrict__ meta, u64* __restrict__ sorted,
                       float4* __restrict__ boxes4, unsigned* __restrict__ vflag) {
    int i = blockIdx.x * blockDim.x + threadIdx.x;
    int total = meta[0];
    if (i >= total) return;
    u64 k = unsorted[i];
    float s = __uint_as_float((unsigned)(k >> 32));
    int b = bucket_of(s);
    unsigned base = off[b];
    unsigned n = histsum[b];
    unsigned r = 0;
    for (unsigned u = 0; u < n; ++u) r += (unsorted[base + u] > k) ? 1u : 0u;
    int bi = (int)(0xFFFFFFFFu - (unsigned)(k & 0xFFFFFFFFull));
    const float* p = in + (size_t)bi * NFEAT;
    float4 bx = make_float4(p[0], p[1], p[2], p[3]);  // y1,x1,y2,x2
    sorted[base + r] = k;
    boxes4[base + r] = bx;
    vflag[base + r] = (bx.z > bx.x && bx.w > bx.y) ? 1u : 0u;
}

// Prefix-scan valid flags; build compact map + compact boxes; meta[3] = nvalid.
// Degenerate boxes have IoU==0 with everything: never suppress, never suppressed
// -> excluded from masks/sweep, always kept.
__global__ void __launch_bounds__(1024) k_vscan(const unsigned* __restrict__ vflag,
        const float4* __restrict__ boxes4, int* __restrict__ meta,
        unsigned* __restrict__ vincl, unsigned* __restrict__ cmap,
        float4* __restrict__ cboxes) {
    __shared__ unsigned ps[1024];
    int t = threadIdx.x;
    int total = meta[0];
    unsigned f[8];
    unsigned run = 0;
    #pragma unroll
    for (int e = 0; e < 8; ++e) {
        int s = t * 8 + e;
        unsigned v = (s < total) ? vflag[s] : 0u;
        run += v;
        f[e] = run;
    }
    ps[t] = run;
    __syncthreads();
    for (int o = 1; o < 1024; o <<= 1) {
        unsigned add = (t >= o) ? ps[t - o] : 0u;
        __syncthreads();
        ps[t] += add;
        __syncthreads();
    }
    unsigned excl = (t > 0) ? ps[t - 1] : 0u;
    #pragma unroll
    for (int e = 0; e < 8; ++e) {
        int s = t * 8 + e;
        unsigned incl = excl + f[e];
        vincl[s] = incl;
        if (s < total && vflag[s]) {
            cmap[incl - 1] = (unsigned)s;
            cboxes[incl - 1] = boxes4[s];
        }
    }
    if (t == 1023) meta[3] = (int)ps[1023];
}

// Pairwise masks over COMPACT valid candidates: masks[i][w] bit b = (j=w*64+b) > i
// && IoU>0.5. Words tj >= ti written; sub-diagonal garbage never effectively read.
__global__ void __launch_bounds__(256) k_masks(const float4* __restrict__ cboxes,
        const int* __restrict__ meta, u64* __restrict__ masks) {
    int ti = blockIdx.y, tj = blockIdx.x;
    if (tj < ti) return;
    int count = meta[3];
    if (ti * 64 >= count) return;
    __shared__ float4 rb[64];
    int t = threadIdx.x;
    if (t < 64) {
        int r = ti * 64 + t;
        rb[t] = (r < count) ? cboxes[r] : make_float4(0.f, 0.f, 0.f, 0.f);
    }
    int lane = t & 63, wid = t >> 6;
    int cj = tj * 64 + lane;
    bool cvalid = (cj < count);
    float4 cb = cvalid ? cboxes[cj] : make_float4(0.f, 0.f, 0.f, 0.f);
    float carea = (cb.z - cb.x) * (cb.w - cb.y);
    __syncthreads();
    #pragma unroll
    for (int r = 0; r < 16; ++r) {
        int i = ti * 64 + wid * 16 + r;
        float4 b = rb[wid * 16 + r];
        float ba = (b.z - b.x) * (b.w - b.y);
        bool s = cvalid && (cj > i) && (i < count) &&
                 sup_iou(b.x, b.y, b.z, b.w, ba, cb.x, cb.y, cb.z, cb.w, carea);
        u64 word = __ballot(s ? 1 : 0);
        if (lane == 0) masks[(size_t)i * W64 + tj] = word;
    }
}

// Wave 0: greedy sweep over compact candidates. Rows are CONTIGUOUS after
// compaction -> stage the whole next block (64 rows x 1 KB) into an LDS double
// buffer with 64 unconditional global_load_lds ops (no registers, no spills --
// R9's register arrays spilled under the 1024-thread VGPR cap). Counted waits:
// issue halfA(w+1) [32 ops] -> vmcnt(32) proves block w landed (vmcnt is 6-bit,
// so a 64-op batch can't be counted in one wait) -> chain -> issue halfB(w+1)
// -> R-update from LDS. Diag word comes from the staged rows themselves.
// Rows padded to 130 u64 so the diag column read is 8-way, not 64-way banked.
// Stops once merged kept (invalids-by-slot + valid-kept) reaches MAXKEEP.
// Then all 1024 threads: finalize scan -> kfinal.
__global__ void __launch_bounds__(1024) k_sweepfin(const u64* __restrict__ masks,
        const unsigned* __restrict__ cmap, const unsigned* __restrict__ vincl,
        const unsigned* __restrict__ vflag, int* __restrict__ meta,
        int* __restrict__ kfinal) {
    __shared__ __align__(16) u64 stage[2][64][130];  // 133120 B
    __shared__ u64 vkeptw[W64];
    __shared__ unsigned ps[1024];
    __shared__ int sh_wlim;
    int t = threadIdx.x;
    if (t < W64) vkeptw[t] = 0ull;
    if (t == 0) sh_wlim = 0;
    __syncthreads();
    int total = meta[0];
    int nv = meta[3];

    if (t < 64) {  // ---- sweep wave ----
        int lane = t;
        int nblkv = (nv + 63) >> 6;
        u64 r0 = 0ull, r1 = 0ull;
        int nkv = 0, wl = 0;

        if (nblkv > 0) {  // prologue: stage block 0 (64 ops)
            #pragma unroll
            for (int k = 0; k < 64; ++k)
                __builtin_amdgcn_global_load_lds(
                    (const __attribute__((address_space(1))) void*)(masks + (size_t)k * W64 + 2 * lane),
                    (__attribute__((address_space(3))) void*)&stage[0][k][0], 16, 0, 0);
        }

        for (int w = 0; w < nblkv; ++w) {
            int buf = w & 1;
            int base = w << 6;
            int rc = nv - base;
            u64 vm = (rc >= 64) ? ~0ull : ((1ull << rc) - 1ull);
            u64 rw = __shfl((w & 1) ? r1 : r0, w >> 1);
            u64 surv = ~rw & vm;
            int cend = (base + 63 < nv - 1) ? (base + 63) : (nv - 1);
            unsigned cm = cmap[cend];
            bool more = (w + 1 < nblkv);
            int base2 = base + 64;

            if (more) {  // half A of block w+1 (32 ops), then counted wait
                #pragma unroll
                for (int k = 0; k < 32; ++k)
                    __builtin_amdgcn_global_load_lds(
                        (const __attribute__((address_space(1))) void*)(masks + (size_t)(base2 + k) * W64 + 2 * lane),
                        (__attribute__((address_space(3))) void*)&stage[buf ^ 1][k][0], 16, 0, 0);
                asm volatile("s_waitcnt vmcnt(32)" ::: "memory");  // block w fully landed
            } else {
                asm volatile("s_waitcnt vmcnt(0)" ::: "memory");
            }
            __builtin_amdgcn_sched_barrier(0);

            u64 diag_cur = stage[buf][lane][w];  // diag word from staged rows
            // in-block greedy chain (nonzero-diag candidates only)
            u64 Z = __ballot(diag_cur == 0ull);
            u64 rem = 0ull;
            u64 mnz = surv & ~Z;
            while (mnz) {
                int b = __ffsll(mnz) - 1;
                mnz &= mnz - 1;
                if ((rem >> b) & 1ull) continue;
                u64 db = __shfl(diag_cur, b);
                rem |= db;
                mnz &= ~db;
            }
            u64 kept = surv & ~rem;
            int kp = __popcll(kept);

            if (more) {  // half B of block w+1 (32 ops), lands during R-update
                #pragma unroll
                for (int k = 32; k < 64; ++k)
                    __builtin_amdgcn_global_load_lds(
                        (const __attribute__((address_space(1))) void*)(masks + (size_t)(base2 + k) * W64 + 2 * lane),
                        (__attribute__((address_space(3))) void*)&stage[buf ^ 1][k][0], 16, 0, 0);
            }

            // R-update: OR kept rows from LDS (lane owns words 2l, 2l+1)
            {
                u64 km = kept;
                u64 alo = 0ull, ahi = 0ull;
                while (km) {
                    int b = __ffsll(km) - 1;
                    km &= km - 1;
                    alo |= stage[buf][b][2 * lane];
                    ahi |= stage[buf][b][2 * lane + 1];
                }
                r0 |= alo; r1 |= ahi;
            }
            if (lane == 0) vkeptw[w] = kept;
            nkv += kp;
            wl = w + 1;
            // merged kept through slot cmap[cend]: invalids (cmap[cend]-cend) + valid-kept
            if ((int)cm - cend + nkv >= MAXKEEP) break;
        }
        if (lane == 0) sh_wlim = wl;
    }
    __syncthreads();
    int wlim = sh_wlim;

    // ---- finalize: kept(s) = invalid(s) OR valid-kept(s); first MAXKEEP ----
    unsigned f[8];
    unsigned run = 0;
    #pragma unroll
    for (int e = 0; e < 8; ++e) {
        int s = t * 8 + e;
        unsigned kept = 0u;
        if (s < total) {
            if (!vflag[s]) kept = 1u;
            else {
                unsigned c = vincl[s] - 1u;
                int w = (int)(c >> 6);
                if (w < wlim && ((vkeptw[w] >> (c & 63u)) & 1ull)) kept = 1u;
            }
        }
        run += kept;
        f[e] = run;
    }
    ps[t] = run;
    __syncthreads();
    for (int o = 1; o < 1024; o <<= 1) {
        unsigned add = (t >= o) ? ps[t - o] : 0u;
        __syncthreads();
        ps[t] += add;
        __syncthreads();
    }
    unsigned excl = (t > 0) ? ps[t - 1] : 0u;
    #pragma unroll
    for (int e = 0; e < 8; ++e) {
        int s = t * 8 + e;
        unsigned kept = 0u;
        if (s < total) {
            if (!vflag[s]) kept = 1u;
            else {
                unsigned c = vincl[s] - 1u;
                int w = (int)(c >> 6);
                if (w < wlim && ((vkeptw[w] >> (c & 63u)) & 1ull)) kept = 1u;
            }
        }
        unsigned incl = excl + f[e];
        if (kept && incl <= (unsigned)MAXKEEP) kfinal[incl - 1] = s;
    }
    if (t == 1023) {
        unsigned tot = ps[1023];
        meta[2] = (int)(tot < (unsigned)MAXKEEP ? tot : (unsigned)MAXKEEP);
    }
}

// One wave per output row: butterfly argmax, strict-greater / lower-index
// tiebreak (== jnp.argmax first occurrence).
__global__ void __launch_bounds__(256) k_output(const float* __restrict__ in,
        const u64* __restrict__ gkeys, const int* __restrict__ meta,
        const int* __restrict__ kfinal, float* __restrict__ out) {
    int gw = (blockIdx.x * blockDim.x + threadIdx.x) >> 6;
    int lane = threadIdx.x & 63;
    if (gw >= MAXKEEP) return;
    int kc = meta[2];
    if (gw < kc) {
        int pos = kfinal[gw];
        u64 key = gkeys[pos];
        int bi = (int)(0xFFFFFFFFu - (unsigned)(key & 0xFFFFFFFFull));
        const float* row = in + (size_t)bi * NFEAT;
        float conf = row[4];
        float v0 = (lane < NCLS) ? conf * row[5 + lane] : -1.0f;
        float v1 = (lane < NCLS - 64) ? conf * row[5 + 64 + lane] : -1.0f;
        float bv = (v1 > v0) ? v1 : v0;
        int bix = (v1 > v0) ? (64 + lane) : lane;
        #pragma unroll
        for (int o = 1; o < 64; o <<= 1) {
            float ov = __shfl_xor(bv, o);
            int oi = __shfl_xor(bix, o);
            if (ov > bv || (ov == bv && oi < bix)) { bv = ov; bix = oi; }
        }
        float wv = 0.f;
        if (lane < 4) wv = row[lane];
        else if (lane == 4) wv = (float)bix;
        else wv = bv;
        if (lane < 6) out[gw * 6 + lane] = wv;
    } else {
        if (lane < 6) out[gw * 6 + lane] = 0.f;
    }
}

extern "C" void kernel_launch(void* const* d_in, const int* in_sizes, int n_in,
                              void* d_out, int out_size, void* d_ws, size_t ws_size,
                              hipStream_t stream) {
    const float* in = (const float*)d_in[0];
    float* out = (float*)d_out;
    char* ws = (char*)d_ws;
    // ws layout (bytes). masks OVERLAYS sort-phase scratch (all dead before k_masks).
    //   [0, 65536)           sorted   u64[8192]
    //   [65536, 65600)       meta     i32[16] {0:total,1:bstar,2:kc,3:nvalid}
    //   [65600, 69696)       kfinal   i32[1024]
    //   [69696, 102464)      vflag    u32[8192]
    //   [102464, 135232)     vincl    u32[8192]
    //   [135232, 168000)     cmap     u32[8192]
    //   [168000, 299072)     cboxes   float4[8192]
    //   [299072, 430144)     boxes4   float4[8192]
    //   [430144, 8818752)    masks    u64[8192*128] (8 MB), overlaying:
    //     [430144, 1630144)    scores   f32[300000]
    //     [1630144, 1892288)   hist16   u32[16*4096]
    //     [1892288, 1908672)   histsum  u32[4096]
    //     [1908672, 1925056)   cnt      u32[4096]
    //     [1925056, 1941440)   off      u32[4096]
    //     [1941440, 2006976)   unsorted u64[8192]
    u64* sorted = (u64*)(ws);
    int* meta = (int*)(ws + 65536);
    int* kfinal = (int*)(ws + 65600);
    unsigned* vflag = (unsigned*)(ws + 69696);
    unsigned* vincl = (unsigned*)(ws + 102464);
    unsigned* cmap = (unsigned*)(ws + 135232);
    float4* cboxes = (float4*)(ws + 168000);
    float4* boxes4 = (float4*)(ws + 299072);
    u64* masks = (u64*)(ws + 430144);
    float* scores = (float*)(ws + 430144);
    unsigned* hist16 = (unsigned*)(ws + 1630144);
    unsigned* histsum = (unsigned*)(ws + 1892288);
    unsigned* cnt = (unsigned*)(ws + 1908672);
    unsigned* off = (unsigned*)(ws + 1925056);
    u64* unsorted = (u64*)(ws + 1941440);

    k_init<<<dim3(256), dim3(256), 0, stream>>>(hist16, cnt, meta);
    k_scores<<<dim3((NBOX + SC_ROWS - 1) / SC_ROWS), dim3(256), 0, stream>>>(in, scores, hist16);
    k_thresh<<<dim3(1), dim3(1024), 0, stream>>>(hist16, histsum, off, meta);
    k_scatter<<<dim3((NBOX + 255) / 256), dim3(256), 0, stream>>>(scores, meta, off, cnt, unsorted);
    k_rank<<<dim3(CMAX / 256), dim3(256), 0, stream>>>(in, unsorted, off, histsum, meta, sorted, boxes4, vflag);
    k_vscan<<<dim3(1), dim3(1024), 0, stream>>>(vflag, boxes4, meta, vincl, cmap, cboxes);
    k_masks<<<dim3(W64, W64), dim3(256), 0, stream>>>(cboxes, meta, masks);
    k_sweepfin<<<dim3(1), dim3(1024), 0, stream>>>(masks, cmap, vincl, vflag, meta, kfinal);
    k_output<<<dim3((MAXKEEP * 64 + 255) / 256), dim3(256), 0, stream>>>(in, sorted, meta, kfinal, out);
}